// Round 5
// baseline (7992.805 us; speedup 1.0000x reference)
//
#include <hip/hip_runtime.h>
#include <hip/hip_bf16.h>

#define NN   12800   // B*L sequences
#define TT   20      // chars per sequence
#define HID  128     // E == H == 128
#define SPB  16      // sequences per block

// One direction per launch. Block: 256 threads = (u:128) x (half:2);
// thread (u, half) computes gates for unit u of 8 sequences (half*8 .. half*8+7).
// Weights read directly in original (4H, E) row-major layout — no repacking.
__global__ __launch_bounds__(256) void bilstm_simple(
    const int*   __restrict__ x,      // [NN][TT] int32
    const float* __restrict__ embed,  // [512][128]
    const float* __restrict__ Wih,    // [512][128] this direction
    const float* __restrict__ Whh,    // [512][128]
    const float* __restrict__ bias,   // [512]
    const int dir,
    float* __restrict__ out)          // [NN][256]  fp32 (reference output dtype)
{
    __shared__ __align__(16) float emb_sh[SPB][HID];
    __shared__ __align__(16) float h_sh[SPB][HID];
    __shared__ int len_sh[SPB];

    const int tid  = threadIdx.x;      // 0..255
    const int u    = tid & 127;        // hidden unit
    const int half = tid >> 7;         // 0 or 1
    const int n0   = blockIdx.x * SPB;
    const int sb   = half * 8;         // first sequence owned by this thread

    // valid-length = COUNT of x>0 over all t (reference semantics)
    if (tid < SPB) {
        int l = 0;
        for (int t = 0; t < TT; ++t) l += (x[(n0 + tid) * TT + t] > 0) ? 1 : 0;
        len_sh[tid] = l;
    }
    for (int i = tid; i < SPB * HID; i += 256) h_sh[i / HID][i % HID] = 0.0f;

    float c[8];
    #pragma unroll
    for (int q = 0; q < 8; ++q) c[q] = 0.0f;

    const float bi = bias[u];
    const float bf = bias[128 + u];
    const float bg = bias[256 + u];
    const float bo = bias[384 + u];

    const float4* Wi4 = reinterpret_cast<const float4*>(Wih);  // row r -> Wi4[r*32 + k4]
    const float4* Wh4 = reinterpret_cast<const float4*>(Whh);

    __syncthreads();

    for (int step = 0; step < TT; ++step) {
        const int t = dir ? (TT - 1 - step) : step;

        // ---- stage emb(t): 256 threads x 8 floats = 16 seq x 128 ----
        {
            const int s  = tid >> 4;        // 0..15
            const int e0 = (tid & 15) * 8;  // 0..120
            const int idx = x[(n0 + s) * TT + t];
            const float4* src = reinterpret_cast<const float4*>(embed + idx * HID + e0);
            float4* dst = reinterpret_cast<float4*>(&emb_sh[s][e0]);
            dst[0] = src[0];
            dst[1] = src[1];
        }
        __syncthreads();

        // ---- gates: g = Wih @ emb + Whh @ h + bias ----
        float gi[8], gf[8], gg[8], go[8];
        #pragma unroll
        for (int q = 0; q < 8; ++q) { gi[q] = bi; gf[q] = bf; gg[q] = bg; go[q] = bo; }

        for (int k4 = 0; k4 < HID / 4; ++k4) {
            const float4 wii = Wi4[(0 * HID + u) * (HID / 4) + k4];
            const float4 wif = Wi4[(1 * HID + u) * (HID / 4) + k4];
            const float4 wig = Wi4[(2 * HID + u) * (HID / 4) + k4];
            const float4 wio = Wi4[(3 * HID + u) * (HID / 4) + k4];
            const float4 whi = Wh4[(0 * HID + u) * (HID / 4) + k4];
            const float4 whf = Wh4[(1 * HID + u) * (HID / 4) + k4];
            const float4 whg = Wh4[(2 * HID + u) * (HID / 4) + k4];
            const float4 who = Wh4[(3 * HID + u) * (HID / 4) + k4];
            #pragma unroll
            for (int q = 0; q < 8; ++q) {
                const int s = sb + q;
                const float4 ev = *reinterpret_cast<const float4*>(&emb_sh[s][k4 * 4]);
                const float4 hv = *reinterpret_cast<const float4*>(&h_sh[s][k4 * 4]);
                gi[q] += wii.x * ev.x + wii.y * ev.y + wii.z * ev.z + wii.w * ev.w
                       + whi.x * hv.x + whi.y * hv.y + whi.z * hv.z + whi.w * hv.w;
                gf[q] += wif.x * ev.x + wif.y * ev.y + wif.z * ev.z + wif.w * ev.w
                       + whf.x * hv.x + whf.y * hv.y + whf.z * hv.z + whf.w * hv.w;
                gg[q] += wig.x * ev.x + wig.y * ev.y + wig.z * ev.z + wig.w * ev.w
                       + whg.x * hv.x + whg.y * hv.y + whg.z * hv.z + whg.w * hv.w;
                go[q] += wio.x * ev.x + wio.y * ev.y + wio.z * ev.z + wio.w * ev.w
                       + who.x * hv.x + who.y * hv.y + who.z * hv.z + who.w * hv.w;
            }
        }
        __syncthreads();

        // ---- masked state update ----
        #pragma unroll
        for (int q = 0; q < 8; ++q) {
            const int s = sb + q;
            if (t < len_sh[s]) {
                const float iv = 1.0f / (1.0f + expf(-gi[q]));
                const float fv = 1.0f / (1.0f + expf(-gf[q]));
                const float gv = tanhf(gg[q]);
                const float ov = 1.0f / (1.0f + expf(-go[q]));
                const float cn = fv * c[q] + iv * gv;
                c[q] = cn;
                h_sh[s][u] = ov * tanhf(cn);
            }
        }
        __syncthreads();
    }

    // ---- final h -> out[n][dir*128 + u], fp32 ----
    #pragma unroll
    for (int q = 0; q < 8; ++q) {
        const int s = sb + q;
        out[(n0 + s) * 256 + dir * HID + u] = h_sh[s][u];
    }
}

extern "C" void kernel_launch(void* const* d_in, const int* in_sizes, int n_in,
                              void* d_out, int out_size, void* d_ws, size_t ws_size,
                              hipStream_t stream)
{
    const int*   x     = (const int*)  d_in[0];
    const float* embed = (const float*)d_in[1];
    const float* Wih_f = (const float*)d_in[2];
    const float* Whh_f = (const float*)d_in[3];
    const float* b_f   = (const float*)d_in[4];
    const float* Wih_b = (const float*)d_in[5];
    const float* Whh_b = (const float*)d_in[6];
    const float* b_b   = (const float*)d_in[7];
    float* out = (float*)d_out;

    bilstm_simple<<<NN / SPB, 256, 0, stream>>>(x, embed, Wih_f, Whh_f, b_f, 0, out);
    bilstm_simple<<<NN / SPB, 256, 0, stream>>>(x, embed, Wih_b, Whh_b, b_b, 1, out);
}

// Round 6
// 260.718 us; speedup vs baseline: 30.6569x; 30.6569x over previous
//
#include <hip/hip_runtime.h>
#include <hip/hip_bf16.h>

#define NN   12800
#define TT   20
#define HID  128
#define SPB  16     // seqs per block (one 16-row M tile)

typedef __attribute__((ext_vector_type(8))) short          bf16x8;
typedef __attribute__((ext_vector_type(8))) unsigned short ushort8;
typedef __attribute__((ext_vector_type(4))) float          f32x4;

// proj table, gate-remapped: projR[d][v][(g&3)*128 + (g>>2)] = bias[g] + sum_e Wih[g][e]*embed[v][e]
__device__ float g_projR[2 * 512 * 512];
// Whh packed as MFMA B-fragments (bf16 bits):
// [(((d*4+w)*8+nt)*4+kt)*64+lane][i] = Whh_d[(nt*16+(lane&15))*4+w][kt*32+(lane>>4)*8+i]
__device__ __align__(16) unsigned short g_Bpk[2 * 4 * 8 * 4 * 64 * 8];

__device__ __forceinline__ unsigned short f2bf(float f) {
    union { float f; unsigned u; } a; a.f = f;
    unsigned r = a.u + 0x7FFF + ((a.u >> 16) & 1);
    return (unsigned short)(r >> 16);
}
__device__ __forceinline__ float sigm(float v)  { return 1.0f / (1.0f + __expf(-v)); }
__device__ __forceinline__ float tanh_(float v) { return 2.0f / (1.0f + __expf(-2.0f * v)) - 1.0f; }

// ---- prep 1: char -> gate-preact table (includes bias), gate-remapped ----
__global__ void prep_proj(const float* __restrict__ embed,
                          const float* __restrict__ Wih_f, const float* __restrict__ b_f,
                          const float* __restrict__ Wih_b, const float* __restrict__ b_b)
{
    const int v = blockIdx.x;   // char 0..511
    const int d = blockIdx.y;   // dir
    const int g = threadIdx.x;  // gate 0..511
    __shared__ float ev[HID];
    if (g < HID) ev[g] = embed[v * HID + g];
    __syncthreads();
    const float* Wi = d ? Wih_b : Wih_f;
    const float* bb = d ? b_b   : b_f;
    float a = bb[g];
    #pragma unroll 8
    for (int e = 0; e < HID; ++e) a = fmaf(Wi[g * HID + e], ev[e], a);
    g_projR[(d * 512 + v) * 512 + (g & 3) * 128 + (g >> 2)] = a;
}

// ---- prep 2: pack Whh into per-wave B fragments (bf16) ----
__global__ void prep_bpack(const float* __restrict__ Whh_f, const float* __restrict__ Whh_b)
{
    const int id = blockIdx.x * 256 + threadIdx.x;   // 0..16383 lane-slots
    const int lane = id & 63;
    const int kt   = (id >> 6) & 3;
    (void)kt;
    const int nt   = (id >> 8) & 7;
    const int w    = (id >> 11) & 3;
    const int d    = id >> 13;
    const float* Wh = d ? Whh_b : Whh_f;
    const int gB = (nt * 16 + (lane & 15)) * 4 + w;
    const int k0 = ((id >> 6) & 3) * 32 + (lane >> 4) * 8;
    ushort8 o;
    #pragma unroll
    for (int i = 0; i < 8; ++i) o[i] = f2bf(Wh[gB * HID + k0 + i]);
    reinterpret_cast<ushort8*>(g_Bpk)[id] = o;
}

// ---- main: 16 seqs/block, 4 waves; wave w owns gates g==w (mod 4) ----
__global__ __launch_bounds__(256, 2) void lstm_mfma(
    const int* __restrict__ x, float* __restrict__ out)
{
    __shared__ __align__(16) unsigned short h_lds[SPB * 136];  // bf16 h, padded rows
    __shared__ int chars[SPB * TT];
    __shared__ int len_sh[SPB];

    const int tid  = threadIdx.x;
    const int lane = tid & 63;
    const int w    = tid >> 6;         // wave id
    const int c0   = lane & 15;        // tile col / A row
    const int rg   = lane >> 4;        // row group
    const int dir  = blockIdx.y;
    const int n0   = blockIdx.x * SPB;

    for (int i = tid; i < SPB * TT; i += 256) chars[i] = x[n0 * TT + i];
    for (int i = tid; i < SPB * 136; i += 256) h_lds[i] = 0;
    __syncthreads();
    if (tid < SPB) {
        int l = 0;
        #pragma unroll
        for (int t = 0; t < TT; ++t) l += (chars[tid * TT + t] > 0) ? 1 : 0;
        len_sh[tid] = l;
    }

    // resident B fragments: 8 n-tiles x 4 k-frags
    bf16x8 B[8][4];
    {
        const bf16x8* Bp = reinterpret_cast<const bf16x8*>(g_Bpk);
        #pragma unroll
        for (int nt = 0; nt < 8; ++nt)
            #pragma unroll
            for (int kt = 0; kt < 4; ++kt)
                B[nt][kt] = Bp[((((dir * 4 + w) * 8 + nt) * 4 + kt) * 64) + lane];
    }
    __syncthreads();

    int len4[4];
    #pragma unroll
    for (int r = 0; r < 4; ++r) len4[r] = len_sh[rg * 4 + r];

    float cst[2][4]  = {};   // cell state, [p][r]
    float hreg[2][4] = {};   // fp32 h copy for final output

    for (int step = 0; step < TT; ++step) {
        const int t = dir ? (TT - 1 - step) : step;

        // A fragments from previous h (bf16)
        bf16x8 A[4];
        #pragma unroll
        for (int kt = 0; kt < 4; ++kt)
            A[kt] = *reinterpret_cast<const bf16x8*>(&h_lds[c0 * 136 + kt * 32 + rg * 8]);

        // C-init from proj table (gates = proj[char] ; remapped cols)
        f32x4 acc[8];
        #pragma unroll
        for (int r = 0; r < 4; ++r) {
            const int ch = chars[(rg * 4 + r) * TT + t];
            const float* prow = g_projR + (dir * 512 + ch) * 512 + w * 128 + c0;
            #pragma unroll
            for (int nt = 0; nt < 8; ++nt) acc[nt][r] = prow[nt * 16];
        }
        __syncthreads();   // all A-reads done before this step's h writes

        #pragma unroll
        for (int kt = 0; kt < 4; ++kt)
            #pragma unroll
            for (int nt = 0; nt < 8; ++nt)
                acc[nt] = __builtin_amdgcn_mfma_f32_16x16x32_bf16(A[kt], B[nt][kt], acc[nt], 0, 0, 0);

        // lane-local LSTM update: quad (p,r) -> unit u = p*64 + c0*4 + w, seq s = rg*4+r
        #pragma unroll
        for (int p = 0; p < 2; ++p) {
            #pragma unroll
            for (int r = 0; r < 4; ++r) {
                const float iv = sigm(acc[0 + p][r]);
                const float fv = sigm(acc[2 + p][r]);
                const float gv = tanh_(acc[4 + p][r]);
                const float ov = sigm(acc[6 + p][r]);
                const float cn = fv * cst[p][r] + iv * gv;
                const float hn = ov * tanh_(cn);
                const bool valid = (t < len4[r]);
                cst[p][r]  = valid ? cn : cst[p][r];
                hreg[p][r] = valid ? hn : hreg[p][r];
                h_lds[(rg * 4 + r) * 136 + p * 64 + c0 * 4 + w] = f2bf(hreg[p][r]);
            }
        }
        __syncthreads();   // h writes visible to next step's A-reads
    }

    #pragma unroll
    for (int p = 0; p < 2; ++p)
        #pragma unroll
        for (int r = 0; r < 4; ++r)
            out[(n0 + rg * 4 + r) * 256 + dir * 128 + p * 64 + c0 * 4 + w] = hreg[p][r];
}

extern "C" void kernel_launch(void* const* d_in, const int* in_sizes, int n_in,
                              void* d_out, int out_size, void* d_ws, size_t ws_size,
                              hipStream_t stream)
{
    const int*   x     = (const int*)  d_in[0];
    const float* embed = (const float*)d_in[1];
    const float* Wih_f = (const float*)d_in[2];
    const float* Whh_f = (const float*)d_in[3];
    const float* b_f   = (const float*)d_in[4];
    const float* Wih_b = (const float*)d_in[5];
    const float* Whh_b = (const float*)d_in[6];
    const float* b_b   = (const float*)d_in[7];
    float* out = (float*)d_out;

    prep_proj <<<dim3(512, 2), 512, 0, stream>>>(embed, Wih_f, b_f, Wih_b, b_b);
    prep_bpack<<<64, 256, 0, stream>>>(Whh_f, Whh_b);
    lstm_mfma <<<dim3(NN / SPB, 2), 256, 0, stream>>>(x, out);
}

// Round 7
// 168.860 us; speedup vs baseline: 47.3340x; 1.5440x over previous
//
#include <hip/hip_runtime.h>
#include <hip/hip_bf16.h>

#define NN   12800
#define TT   20
#define HID  128
#define SPB  16     // seqs per block (one 16-row M tile)

typedef __attribute__((ext_vector_type(8))) short          bf16x8;
typedef __attribute__((ext_vector_type(8))) unsigned short ushort8;
typedef __attribute__((ext_vector_type(4))) float          f32x4;

// proj table, vectorized layout:
// g_projV[((d*512+v)*4 + w)*128 + c0*8 + nt] = bias[g] + sum_e Wih[g][e]*embed[v][e]
// where g = (nt*16 + c0)*4 + w   (wave w owns gates g ≡ w mod 4)
__device__ float g_projV[2 * 512 * 4 * 128];
// Whh packed as MFMA B-fragments (bf16 bits):
// [(((d*4+w)*8+nt)*4+kt)*64+lane][i] = Whh_d[(nt*16+(lane&15))*4+w][kt*32+(lane>>4)*8+i]
__device__ __align__(16) unsigned short g_Bpk[2 * 4 * 8 * 4 * 64 * 8];

__device__ __forceinline__ unsigned short f2bf(float f) {
    union { float f; unsigned u; } a; a.f = f;
    unsigned r = a.u + 0x7FFF + ((a.u >> 16) & 1);
    return (unsigned short)(r >> 16);
}
// fast sigmoid/tanh: v_exp + v_rcp (no IEEE div expansion)
__device__ __forceinline__ float sigm(float v) {
    return __builtin_amdgcn_rcpf(1.0f + __expf(-v));
}
__device__ __forceinline__ float tanh_(float v) {
    return fmaf(2.0f, __builtin_amdgcn_rcpf(1.0f + __expf(-2.0f * v)), -1.0f);
}

// ---- prep 1: char -> gate-preact table (includes bias), vector layout ----
__global__ void prep_proj(const float* __restrict__ embed,
                          const float* __restrict__ Wih_f, const float* __restrict__ b_f,
                          const float* __restrict__ Wih_b, const float* __restrict__ b_b)
{
    const int v = blockIdx.x;   // char 0..511
    const int d = blockIdx.y;   // dir
    const int g = threadIdx.x;  // gate 0..511
    __shared__ float ev[HID];
    if (g < HID) ev[g] = embed[v * HID + g];
    __syncthreads();
    const float* Wi = d ? Wih_b : Wih_f;
    const float* bb = d ? b_b   : b_f;
    float a = bb[g];
    #pragma unroll 8
    for (int e = 0; e < HID; ++e) a = fmaf(Wi[g * HID + e], ev[e], a);
    // g = n*4+w, n = nt*16+c0:  w=g&3, c0=(g>>2)&15, nt=g>>6
    g_projV[((d * 512 + v) * 4 + (g & 3)) * 128 + ((g >> 2) & 15) * 8 + (g >> 6)] = a;
}

// ---- prep 2: pack Whh into per-wave B fragments (bf16) ----
__global__ void prep_bpack(const float* __restrict__ Whh_f, const float* __restrict__ Whh_b)
{
    const int id = blockIdx.x * 256 + threadIdx.x;   // 0..16383 lane-slots
    const int lane = id & 63;
    const int nt   = (id >> 8) & 7;
    const int w    = (id >> 11) & 3;
    const int d    = id >> 13;
    const float* Wh = d ? Whh_b : Whh_f;
    const int gB = (nt * 16 + (lane & 15)) * 4 + w;
    const int k0 = ((id >> 6) & 3) * 32 + (lane >> 4) * 8;
    ushort8 o;
    #pragma unroll
    for (int i = 0; i < 8; ++i) o[i] = f2bf(Wh[gB * HID + k0 + i]);
    reinterpret_cast<ushort8*>(g_Bpk)[id] = o;
}

// one LSTM step; HC/HN = LDS h ping-pong, QC = this step's proj regs,
// QN = prefetch target for step tn. All names static (unroll-2).
#define STEP(tc, QC, QN, tn, HC, HN)                                          \
{                                                                             \
    bf16x8 A[4];                                                              \
    _Pragma("unroll")                                                         \
    for (int kt = 0; kt < 4; ++kt)                                            \
        A[kt] = *reinterpret_cast<const bf16x8*>(&HC[c0 * 136 + kt * 32 + rg * 8]); \
    f32x4 acc[8];                                                             \
    _Pragma("unroll")                                                         \
    for (int r = 0; r < 4; ++r) {                                             \
        _Pragma("unroll")                                                     \
        for (int j = 0; j < 4; ++j) {                                         \
            acc[j][r]     = QC[r][0][j];                                      \
            acc[4 + j][r] = QC[r][1][j];                                      \
        }                                                                     \
    }                                                                         \
    _Pragma("unroll")                                                         \
    for (int r = 0; r < 4; ++r) {                                             \
        const int ch = chars[(rg * 4 + r) * TT + (tn)];                       \
        const f32x4* p = reinterpret_cast<const f32x4*>(                      \
            g_projV + ((dir * 512 + ch) * 4 + w) * 128 + c0 * 8);             \
        QN[r][0] = p[0];                                                      \
        QN[r][1] = p[1];                                                      \
    }                                                                         \
    _Pragma("unroll")                                                         \
    for (int kt = 0; kt < 4; ++kt) {                                          \
        _Pragma("unroll")                                                     \
        for (int nt = 0; nt < 8; ++nt)                                        \
            acc[nt] = __builtin_amdgcn_mfma_f32_16x16x32_bf16(A[kt], B[nt][kt], acc[nt], 0, 0, 0); \
    }                                                                         \
    _Pragma("unroll")                                                         \
    for (int p = 0; p < 2; ++p) {                                             \
        _Pragma("unroll")                                                     \
        for (int r = 0; r < 4; ++r) {                                         \
            const float iv = sigm(acc[0 + p][r]);                             \
            const float fv = sigm(acc[2 + p][r]);                             \
            const float gv = tanh_(acc[4 + p][r]);                            \
            const float ov = sigm(acc[6 + p][r]);                             \
            const float cn = fmaf(fv, cst[p][r], iv * gv);                    \
            const float hn = ov * tanh_(cn);                                  \
            const bool valid = ((tc) < len4[r]);                              \
            cst[p][r]  = valid ? cn : cst[p][r];                              \
            hreg[p][r] = valid ? hn : hreg[p][r];                             \
            HN[(rg * 4 + r) * 136 + p * 64 + c0 * 4 + w] = f2bf(hreg[p][r]);  \
        }                                                                     \
    }                                                                         \
    __syncthreads();                                                          \
}

// ---- main: 16 seqs/block, 4 waves; wave w owns gates g==w (mod 4) ----
__global__ __launch_bounds__(256, 2) void lstm_mfma(
    const int* __restrict__ x, float* __restrict__ out)
{
    __shared__ __align__(16) unsigned short h0[SPB * 136];  // bf16 h ping
    __shared__ __align__(16) unsigned short h1[SPB * 136];  // bf16 h pong
    __shared__ int chars[SPB * TT];
    __shared__ int len_sh[SPB];

    const int tid  = threadIdx.x;
    const int lane = tid & 63;
    const int w    = tid >> 6;         // wave id
    const int c0   = lane & 15;        // A row (=seq) / D col
    const int rg   = lane >> 4;        // row group
    const int dir  = blockIdx.y;
    const int n0   = blockIdx.x * SPB;

    for (int i = tid; i < SPB * TT; i += 256) chars[i] = x[n0 * TT + i];
    for (int i = tid; i < SPB * 136; i += 256) { h0[i] = 0; h1[i] = 0; }
    __syncthreads();
    if (tid < SPB) {
        int l = 0;
        #pragma unroll
        for (int t = 0; t < TT; ++t) l += (chars[tid * TT + t] > 0) ? 1 : 0;
        len_sh[tid] = l;
    }

    // resident B fragments: 8 n-tiles x 4 k-frags
    bf16x8 B[8][4];
    {
        const bf16x8* Bp = reinterpret_cast<const bf16x8*>(g_Bpk);
        #pragma unroll
        for (int nt = 0; nt < 8; ++nt)
            #pragma unroll
            for (int kt = 0; kt < 4; ++kt)
                B[nt][kt] = Bp[((((dir * 4 + w) * 8 + nt) * 4 + kt) * 64) + lane];
    }
    __syncthreads();

    int len4[4];
    #pragma unroll
    for (int r = 0; r < 4; ++r) len4[r] = len_sh[rg * 4 + r];

    float cst[2][4]  = {};   // cell state [p][r]
    float hreg[2][4] = {};   // fp32 h copy for final output

    // preload proj for step 0
    f32x4 qA[4][2], qB[4][2];
    {
        const int tfirst = dir ? (TT - 1) : 0;
        #pragma unroll
        for (int r = 0; r < 4; ++r) {
            const int ch = chars[(rg * 4 + r) * TT + tfirst];
            const f32x4* p = reinterpret_cast<const f32x4*>(
                g_projV + ((dir * 512 + ch) * 4 + w) * 128 + c0 * 8);
            qA[r][0] = p[0];
            qA[r][1] = p[1];
        }
    }

    for (int step = 0; step < TT; step += 2) {
        const int t0 = dir ? (TT - 1 - step) : step;
        const int t1 = dir ? (TT - 2 - step) : (step + 1);
        const int t2 = (step + 2 < TT) ? (dir ? (TT - 3 - step) : (step + 2)) : 0;
        STEP(t0, qA, qB, t1, h0, h1)   // uses qA, prefetches t1 into qB
        STEP(t1, qB, qA, t2, h1, h0)   // uses qB, prefetches t2 into qA
    }

    #pragma unroll
    for (int p = 0; p < 2; ++p)
        #pragma unroll
        for (int r = 0; r < 4; ++r)
            out[(n0 + rg * 4 + r) * 256 + dir * 128 + p * 64 + c0 * 4 + w] = hreg[p][r];
}

extern "C" void kernel_launch(void* const* d_in, const int* in_sizes, int n_in,
                              void* d_out, int out_size, void* d_ws, size_t ws_size,
                              hipStream_t stream)
{
    const int*   x     = (const int*)  d_in[0];
    const float* embed = (const float*)d_in[1];
    const float* Wih_f = (const float*)d_in[2];
    const float* Whh_f = (const float*)d_in[3];
    const float* b_f   = (const float*)d_in[4];
    const float* Wih_b = (const float*)d_in[5];
    const float* Whh_b = (const float*)d_in[6];
    const float* b_b   = (const float*)d_in[7];
    float* out = (float*)d_out;

    prep_proj <<<dim3(512, 2), 512, 0, stream>>>(embed, Wih_f, b_f, Wih_b, b_b);
    prep_bpack<<<64, 256, 0, stream>>>(Whh_f, Whh_b);
    lstm_mfma <<<dim3(NN / SPB, 2), 256, 0, stream>>>(x, out);
}